// Round 3
// baseline (651.966 us; speedup 1.0000x reference)
//
#include <hip/hip_runtime.h>
#include <hip/hip_fp16.h>
#include <math.h>

// MSDeformAttn fp32. N=2, C=256, M=8, L=4, P=4, D=32, LEN=21760
// R3: QB=8, compact u16/fp16 descriptors staged via registers, sync-free
//     gather loop, launch_bounds(256,4) for 16 waves/CU.

constexpr int NB  = 2;
constexpr int C   = 256;
constexpr int M   = 8;
constexpr int LV  = 4;
constexpr int P   = 4;
constexpr int D   = 32;
constexpr int LEN = 21760;

// ---------------------------------------------------------------------------
// Kernel 1: value = input_flatten @ W_val + b_val -> value[n][m][pix][d]
// ---------------------------------------------------------------------------
__global__ __launch_bounds__(256) void k_valproj(
    const float* __restrict__ inflat, const float* __restrict__ Wv,
    const float* __restrict__ bv, float* __restrict__ value) {
  __shared__ __align__(16) float rows[16][C];
  const int t  = threadIdx.x;
  const int r0 = blockIdx.x * 16;

  for (int rr = 0; rr < 16; ++rr)
    rows[rr][t] = inflat[(size_t)(r0 + rr) * C + t];
  __syncthreads();

  const int c4    = (t & 63) * 4;
  const int rbase = (t >> 6) * 4;
  float acc[4][4];
#pragma unroll
  for (int r = 0; r < 4; ++r)
#pragma unroll
    for (int c = 0; c < 4; ++c) acc[r][c] = 0.f;

  for (int k = 0; k < C; k += 4) {
    float4 q[4];
#pragma unroll
    for (int r = 0; r < 4; ++r) q[r] = *(const float4*)&rows[rbase + r][k];
#pragma unroll
    for (int kk = 0; kk < 4; ++kk) {
      const float4 w = *(const float4*)&Wv[(size_t)(k + kk) * C + c4];
#pragma unroll
      for (int r = 0; r < 4; ++r) {
        const float qv = ((const float*)&q[r])[kk];
        acc[r][0] += qv * w.x; acc[r][1] += qv * w.y;
        acc[r][2] += qv * w.z; acc[r][3] += qv * w.w;
      }
    }
  }
  const float4 bb = *(const float4*)&bv[c4];
  const int m = c4 >> 5, dd = c4 & 31;
#pragma unroll
  for (int r = 0; r < 4; ++r) {
    const int row = r0 + rbase + r;
    const int n = row / LEN, i = row % LEN;
    float4 o;
    o.x = acc[r][0] + bb.x; o.y = acc[r][1] + bb.y;
    o.z = acc[r][2] + bb.z; o.w = acc[r][3] + bb.w;
    *(float4*)&value[(((size_t)(n * M + m)) * LEN + i) * D + dd] = o;
  }
}

// ---------------------------------------------------------------------------
// Kernel 2: fused offsets/attn GEMM + softmax + compact desc + gather
// block = 8 queries, 256 threads, LDS ~20.25 KiB
// ---------------------------------------------------------------------------
__global__ __launch_bounds__(256, 4) void k_sample(
    const float* __restrict__ query, const float* __restrict__ refp,
    const float* __restrict__ Woff, const float* __restrict__ boff,
    const float* __restrict__ Wattn, const float* __restrict__ battn,
    const float* __restrict__ value, float* __restrict__ accout) {
  __shared__ __align__(16) float smem[5184];  // 20.25 KiB
  float* qrows = smem;          // [8][256] ; later desc (with offs)
  float* offs  = smem + 2048;   // [8][256]
  float* attw  = smem + 4096;   // [8][128]
  float* refs  = smem + 5120;   // [8][8]
  uint4* descp = (uint4*)smem;  // [1024] = 16 KiB, aliases qrows+offs

  const int t  = threadIdx.x;
  const int b  = blockIdx.x;
  const int n  = b / (LEN / 8);
  const int q0 = (b % (LEN / 8)) * 8;

#pragma unroll
  for (int rr = 0; rr < 8; ++rr)
    qrows[rr * C + t] = query[((size_t)n * LEN + q0 + rr) * C + t];
  if (t < 64) refs[t] = refp[((size_t)n * LEN + q0) * 8 + t];
  __syncthreads();

  // ---- fused GEMM: 2 rows x (4 offset cols + 2 attn cols) per thread ----
  {
    const int c4    = (t & 63) * 4;
    const int c2    = (t & 63) * 2;
    const int rbase = (t >> 6) * 2;
    float ao[2][4], aa[2][2];
#pragma unroll
    for (int r = 0; r < 2; ++r) {
#pragma unroll
      for (int c = 0; c < 4; ++c) ao[r][c] = 0.f;
      aa[r][0] = 0.f; aa[r][1] = 0.f;
    }
    for (int k = 0; k < C; k += 4) {
      float4 q[2];
#pragma unroll
      for (int r = 0; r < 2; ++r) q[r] = *(const float4*)&qrows[(rbase + r) * C + k];
#pragma unroll
      for (int kk = 0; kk < 4; ++kk) {
        const float4 w  = *(const float4*)&Woff[(size_t)(k + kk) * 256 + c4];
        const float2 wa = *(const float2*)&Wattn[(size_t)(k + kk) * 128 + c2];
#pragma unroll
        for (int r = 0; r < 2; ++r) {
          const float qv = ((const float*)&q[r])[kk];
          ao[r][0] += qv * w.x; ao[r][1] += qv * w.y;
          ao[r][2] += qv * w.z; ao[r][3] += qv * w.w;
          aa[r][0] += qv * wa.x; aa[r][1] += qv * wa.y;
        }
      }
    }
    const float4 bo4 = *(const float4*)&boff[c4];
    const float2 ba2 = *(const float2*)&battn[c2];
#pragma unroll
    for (int r = 0; r < 2; ++r) {
      float4 o;
      o.x = ao[r][0] + bo4.x; o.y = ao[r][1] + bo4.y;
      o.z = ao[r][2] + bo4.z; o.w = ao[r][3] + bo4.w;
      *(float4*)&offs[(rbase + r) * 256 + c4] = o;
      attw[(rbase + r) * 128 + c2]     = aa[r][0] + ba2.x;
      attw[(rbase + r) * 128 + c2 + 1] = aa[r][1] + ba2.y;
    }
  }
  __syncthreads();

  // ---- softmax over 16 per (q, m): 64 tasks ----
  if (t < 64) {
    const int rr = t >> 3, m = t & 7;
    float v[16], mx = -1e30f;
#pragma unroll
    for (int j = 0; j < 16; ++j) { v[j] = attw[rr * 128 + m * 16 + j]; mx = fmaxf(mx, v[j]); }
    float s = 0.f;
#pragma unroll
    for (int j = 0; j < 16; ++j) { v[j] = __expf(v[j] - mx); s += v[j]; }
    const float inv = 1.f / s;
#pragma unroll
    for (int j = 0; j < 16; ++j) attw[rr * 128 + m * 16 + j] = v[j] * inv;
  }
  __syncthreads();

  // ---- descriptor build (registers), 4 per thread ----
  uint4 dreg[4];
#pragma unroll
  for (int k2 = 0; k2 < 4; ++k2) {
    const int e  = t + k2 * 256;
    const int q  = e >> 7, qq = e & 127;
    const int m = qq & 7, j = qq >> 3, l = j >> 2;
    const int jo = m * 16 + j;
    const float ox = offs[q * 256 + 2 * jo], oy = offs[q * 256 + 2 * jo + 1];
    const float aw = attw[q * 128 + jo];
    const float rx = refs[q * 8 + l * 2 + 0], ry = refs[q * 8 + l * 2 + 1];
    const int W = 128 >> l;
    const int st_l = ((16384 - (16384 >> (2 * l))) * 4) / 3;  // 0,16384,20480,21504
    const float x = rx * (float)W + ox - 0.5f;
    const float y = ry * (float)W + oy - 0.5f;
    const float x0f = floorf(x), y0f = floorf(y);
    const float fx = x - x0f, fy = y - y0f;
    const int x0 = (int)x0f, y0 = (int)y0f;
    const int x1 = x0 + 1, y1 = y0 + 1;
    const int x0c = min(max(x0, 0), W - 1), x1c = min(max(x1, 0), W - 1);
    const int y0c = min(max(y0, 0), W - 1), y1c = min(max(y1, 0), W - 1);
    float wx0 = 1.f - fx, wx1 = fx, wy0 = 1.f - fy, wy1 = fy;
    if (x0 < 0 || x0 >= W) wx0 = 0.f;
    if (x1 < 0 || x1 >= W) wx1 = 0.f;
    if (y0 < 0 || y0 >= W) wy0 = 0.f;
    if (y1 < 0 || y1 >= W) wy1 = 0.f;
    const uint32_t i00 = (uint32_t)(st_l + y0c * W + x0c);
    const uint32_t i01 = (uint32_t)(st_l + y0c * W + x1c);
    const uint32_t i10 = (uint32_t)(st_l + y1c * W + x0c);
    const uint32_t i11 = (uint32_t)(st_l + y1c * W + x1c);
    union { __half2 h; uint32_t u; } p0, p1;
    p0.h = __floats2half2_rn(wx0 * wy0 * aw, wx1 * wy0 * aw);
    p1.h = __floats2half2_rn(wx0 * wy1 * aw, wx1 * wy1 * aw);
    dreg[k2].x = i00 | (i01 << 16);
    dreg[k2].y = i10 | (i11 << 16);
    dreg[k2].z = p0.u;
    dreg[k2].w = p1.u;
  }
  __syncthreads();   // offs/attw fully consumed
#pragma unroll
  for (int k2 = 0; k2 < 4; ++k2) descp[t + k2 * 256] = dreg[k2];
  __syncthreads();

  // ---- gather + weighted accumulate, no further barriers ----
  const int qw = t >> 6;            // wave id -> base query
  const int mB = (t >> 3) & 7;
  const int d4 = t & 7;
  const uint32_t baseoff =
      ((uint32_t)((n * M + mB) * LEN) * D + (uint32_t)d4 * 4) * 4u;  // bytes
  const char* vbase = (const char*)value;

  for (int qc = 0; qc < 2; ++qc) {
    const int q = qw + qc * 4;
    float4 acc = {0.f, 0.f, 0.f, 0.f};
#pragma unroll
    for (int j = 0; j < 16; ++j) {
      const uint4 dsc = descp[q * 128 + j * 8 + mB];
      const uint32_t i00 = dsc.x & 0xffffu, i01 = dsc.x >> 16;
      const uint32_t i10 = dsc.y & 0xffffu, i11 = dsc.y >> 16;
      union { uint32_t u; __half2 h; } pz, pw;
      pz.u = dsc.z; pw.u = dsc.w;
      const float2 w01 = __half22float2(pz.h);
      const float2 w23 = __half22float2(pw.h);
      const float4 v00 = *(const float4*)(vbase + baseoff + (i00 << 7));
      const float4 v01 = *(const float4*)(vbase + baseoff + (i01 << 7));
      const float4 v10 = *(const float4*)(vbase + baseoff + (i10 << 7));
      const float4 v11 = *(const float4*)(vbase + baseoff + (i11 << 7));
      acc.x += w01.x * v00.x; acc.y += w01.x * v00.y; acc.z += w01.x * v00.z; acc.w += w01.x * v00.w;
      acc.x += w01.y * v01.x; acc.y += w01.y * v01.y; acc.z += w01.y * v01.z; acc.w += w01.y * v01.w;
      acc.x += w23.x * v10.x; acc.y += w23.x * v10.y; acc.z += w23.x * v10.z; acc.w += w23.x * v10.w;
      acc.x += w23.y * v11.x; acc.y += w23.y * v11.y; acc.z += w23.y * v11.z; acc.w += w23.y * v11.w;
    }
    *(float4*)&accout[((size_t)n * LEN + q0 + q) * C + mB * 32 + d4 * 4] = acc;
  }
}

// ---------------------------------------------------------------------------
// Kernel 3: out = acc @ W_out + b_out
// ---------------------------------------------------------------------------
__global__ __launch_bounds__(256) void k_outproj(
    const float* __restrict__ accin, const float* __restrict__ Wo,
    const float* __restrict__ bo, float* __restrict__ out) {
  __shared__ __align__(16) float rows[16][C];
  const int t  = threadIdx.x;
  const int r0 = blockIdx.x * 16;

  for (int rr = 0; rr < 16; ++rr)
    rows[rr][t] = accin[(size_t)(r0 + rr) * C + t];
  __syncthreads();

  const int c4    = (t & 63) * 4;
  const int rbase = (t >> 6) * 4;
  float acc[4][4];
#pragma unroll
  for (int r = 0; r < 4; ++r)
#pragma unroll
    for (int c = 0; c < 4; ++c) acc[r][c] = 0.f;

  for (int k = 0; k < C; k += 4) {
    float4 q[4];
#pragma unroll
    for (int r = 0; r < 4; ++r) q[r] = *(const float4*)&rows[rbase + r][k];
#pragma unroll
    for (int kk = 0; kk < 4; ++kk) {
      const float4 w = *(const float4*)&Wo[(size_t)(k + kk) * C + c4];
#pragma unroll
      for (int r = 0; r < 4; ++r) {
        const float qv = ((const float*)&q[r])[kk];
        acc[r][0] += qv * w.x; acc[r][1] += qv * w.y;
        acc[r][2] += qv * w.z; acc[r][3] += qv * w.w;
      }
    }
  }
  const float4 bb = *(const float4*)&bo[c4];
#pragma unroll
  for (int r = 0; r < 4; ++r) {
    const size_t row = (size_t)(r0 + rbase + r);
    float4 o;
    o.x = acc[r][0] + bb.x; o.y = acc[r][1] + bb.y;
    o.z = acc[r][2] + bb.z; o.w = acc[r][3] + bb.w;
    *(float4*)&out[row * C + c4] = o;
  }
}

// ---------------------------------------------------------------------------
extern "C" void kernel_launch(void* const* d_in, const int* in_sizes, int n_in,
                              void* d_out, int out_size, void* d_ws, size_t ws_size,
                              hipStream_t stream) {
  const float* query = (const float*)d_in[0];
  const float* refp  = (const float*)d_in[1];
  const float* infl  = (const float*)d_in[2];
  const float* Woff  = (const float*)d_in[3];
  const float* boff  = (const float*)d_in[4];
  const float* Wattn = (const float*)d_in[5];
  const float* battn = (const float*)d_in[6];
  const float* Wval  = (const float*)d_in[7];
  const float* bval  = (const float*)d_in[8];
  const float* Wout  = (const float*)d_in[9];
  const float* bout  = (const float*)d_in[10];
  float* out = (float*)d_out;

  float* value  = (float*)d_ws;                       // NB*M*LEN*D floats
  float* accbuf = value + (size_t)NB * M * LEN * D;   // NB*LEN*C floats

  k_valproj<<<(NB * LEN) / 16, 256, 0, stream>>>(infl, Wval, bval, value);
  k_sample<<<NB * (LEN / 8), 256, 0, stream>>>(query, refp, Woff, boff,
                                               Wattn, battn, value, accbuf);
  k_outproj<<<(NB * LEN) / 16, 256, 0, stream>>>(accbuf, Wout, bout, out);
}

// Round 4
// 303.447 us; speedup vs baseline: 2.1485x; 2.1485x over previous
//
#include <hip/hip_runtime.h>
#include <hip/hip_fp16.h>
#include <math.h>
#include <stdint.h>

// MSDeformAttn. N=2, C=256, M=8, L=4, P=4, D=32, LEN=21760
// R4: split kernels; bf16 MFMA GEMMs; fp16 value; bf16 acc; chunked descs.

constexpr int NB  = 2;
constexpr int C   = 256;
constexpr int M   = 8;
constexpr int D   = 32;
constexpr int LEN = 21760;
constexpr int QCH = LEN / 4;   // 5440 queries per chunk (per batch)

typedef __attribute__((ext_vector_type(8))) short short8v;
typedef __attribute__((ext_vector_type(4))) float f32x4;

__device__ __forceinline__ short f2bf(float x) {
  uint32_t u = __float_as_uint(x);
  u = (u + 0x7fffu + ((u >> 16) & 1u)) >> 16;
  return (short)u;
}

// ---------------------------------------------------------------------------
// Prepack: dst[c][k] = (bf16) src[k][c]   (src row-major [256][ncols])
// ---------------------------------------------------------------------------
__global__ __launch_bounds__(256) void k_tcast(const float* __restrict__ src,
                                               short* __restrict__ dst, int ncols) {
  __shared__ float tile[32][33];
  const int t = threadIdx.x, tx = t & 31, ty = t >> 5;
  const int c0 = blockIdx.x * 32, k0 = blockIdx.y * 32;
#pragma unroll
  for (int i = 0; i < 4; ++i)
    tile[ty + i * 8][tx] = src[(size_t)(k0 + ty + i * 8) * ncols + c0 + tx];
  __syncthreads();
#pragma unroll
  for (int i = 0; i < 4; ++i)
    dst[(size_t)(c0 + ty + i * 8) * 256 + k0 + tx] = f2bf(tile[tx][ty + i * 8]);
}

// ---------------------------------------------------------------------------
// LDS staging (32 rows x 256 k, bf16, XOR-swizzled) + fragment loads
// ---------------------------------------------------------------------------
__device__ __forceinline__ void stage_cast(const float* __restrict__ p, char* sm, int t) {
  const int r = t >> 3, seg = t & 7;
  const float4* s = (const float4*)(p + (size_t)r * C + seg * 32);
  short v[32];
#pragma unroll
  for (int i = 0; i < 8; ++i) {
    float4 f = s[i];
    v[i * 4 + 0] = f2bf(f.x); v[i * 4 + 1] = f2bf(f.y);
    v[i * 4 + 2] = f2bf(f.z); v[i * 4 + 3] = f2bf(f.w);
  }
#pragma unroll
  for (int i = 0; i < 4; ++i) {
    const int kb = (seg * 32 + i * 8) * 2;
    *(int4*)(sm + r * 512 + (kb ^ ((r & 7) << 4))) = ((const int4*)v)[i];
  }
}

__device__ __forceinline__ void stage_bf16(const short* __restrict__ p, char* sm, int t) {
  const int r = t >> 3, seg = t & 7;
  const int4* s = (const int4*)(p + (size_t)r * C + seg * 32);
#pragma unroll
  for (int i = 0; i < 4; ++i) {
    const int kb = (seg * 32 + i * 8) * 2;
    *(int4*)(sm + r * 512 + (kb ^ ((r & 7) << 4))) = s[i];
  }
}

__device__ __forceinline__ short8v ldsA(const char* sm, int lane, int rt, int ks) {
  const int row = rt * 16 + (lane & 15);
  const int kb  = ks * 64 + ((lane >> 4) << 4);
  const int4 v = *(const int4*)(sm + row * 512 + (kb ^ ((row & 7) << 4)));
  union { int4 i; short8v s; } u; u.i = v; return u.s;
}

__device__ __forceinline__ short8v ldB(const short* __restrict__ WT, int col, int ks, int lane) {
  const int kidx = ks * 32 + ((lane >> 4) << 3);
  const int4 v = *(const int4*)(WT + (size_t)col * 256 + kidx);
  union { int4 i; short8v s; } u; u.i = v; return u.s;
}

// ---------------------------------------------------------------------------
// Kernel: value = bf16mm(input_flatten, WvT) + bv -> fp16 value[n][m][pix][d]
// ---------------------------------------------------------------------------
__global__ __launch_bounds__(256, 4) void k_valproj(
    const float* __restrict__ infl, const short* __restrict__ WvT,
    const float* __restrict__ bv, __half* __restrict__ value) {
  __shared__ __align__(16) char smA[32 * 512];
  const int t = threadIdx.x, lane = t & 63, w = t >> 6;
  const int r0 = blockIdx.x * 32;
  stage_cast(infl + (size_t)r0 * C, smA, t);
  __syncthreads();

  f32x4 acc[2][4];
#pragma unroll
  for (int a = 0; a < 2; ++a)
#pragma unroll
    for (int b = 0; b < 4; ++b) acc[a][b] = (f32x4){0.f, 0.f, 0.f, 0.f};
  const int c0w = w * 64;
#pragma unroll
  for (int ks = 0; ks < 8; ++ks) {
    const short8v a0 = ldsA(smA, lane, 0, ks);
    const short8v a1 = ldsA(smA, lane, 1, ks);
#pragma unroll
    for (int ct = 0; ct < 4; ++ct) {
      const short8v b = ldB(WvT, c0w + ct * 16 + (lane & 15), ks, lane);
      acc[0][ct] = __builtin_amdgcn_mfma_f32_16x16x32_bf16(a0, b, acc[0][ct], 0, 0, 0);
      acc[1][ct] = __builtin_amdgcn_mfma_f32_16x16x32_bf16(a1, b, acc[1][ct], 0, 0, 0);
    }
  }
  const int n = (blockIdx.x >= (LEN / 32)) ? 1 : 0;
  const int pix0 = r0 - n * LEN;
#pragma unroll
  for (int ct = 0; ct < 4; ++ct) {
    const int col = c0w + ct * 16 + (lane & 15);
    const float bb = bv[col];
    const int m = col >> 5, d = col & 31;
    const uint32_t vb = (uint32_t)((n * 8 + m) * LEN) * 32u + (uint32_t)d;
#pragma unroll
    for (int rt = 0; rt < 2; ++rt)
#pragma unroll
      for (int r = 0; r < 4; ++r) {
        const int pix = pix0 + rt * 16 + ((lane >> 4) << 2) + r;
        value[vb + (uint32_t)pix * 32u] = __float2half(acc[rt][ct][r] + bb);
      }
  }
}

// ---------------------------------------------------------------------------
// Kernel: offsets/attn GEMM (bf16 MFMA) + softmax + descriptor build
// block = 32 queries; writes uint4 descriptors for one chunk
// ---------------------------------------------------------------------------
__global__ __launch_bounds__(256, 3) void k_desc(
    const float* __restrict__ query, const float* __restrict__ refp,
    const short* __restrict__ WdT, const float* __restrict__ boff,
    const float* __restrict__ battn, uint4* __restrict__ descD, int qbase) {
  __shared__ __align__(16) char smem[50176];
  char*  smA  = smem;                       // [32][512] bf16 A-tile
  float* offs = (float*)smem;               // [32][256] (aliases smA; used later)
  float* attw = (float*)(smem + 32768);     // [32][128]
  float* refs = (float*)(smem + 49152);     // [32][8]

  const int t = threadIdx.x, lane = t & 63, w = t >> 6;
  const int n   = blockIdx.x / 170;
  const int q0c = (blockIdx.x % 170) * 32;
  const size_t qrow = (size_t)n * LEN + qbase + q0c;

  refs[t] = refp[qrow * 8 + t];
  stage_cast(query + qrow * C, smA, t);
  __syncthreads();

  f32x4 acc[2][6];
#pragma unroll
  for (int a = 0; a < 2; ++a)
#pragma unroll
    for (int b = 0; b < 6; ++b) acc[a][b] = (f32x4){0.f, 0.f, 0.f, 0.f};
  const int c0w = w * 96;
#pragma unroll
  for (int ks = 0; ks < 8; ++ks) {
    const short8v a0 = ldsA(smA, lane, 0, ks);
    const short8v a1 = ldsA(smA, lane, 1, ks);
#pragma unroll
    for (int ct = 0; ct < 6; ++ct) {
      const short8v b = ldB(WdT, c0w + ct * 16 + (lane & 15), ks, lane);
      acc[0][ct] = __builtin_amdgcn_mfma_f32_16x16x32_bf16(a0, b, acc[0][ct], 0, 0, 0);
      acc[1][ct] = __builtin_amdgcn_mfma_f32_16x16x32_bf16(a1, b, acc[1][ct], 0, 0, 0);
    }
  }
  __syncthreads();   // all LDS A reads complete before aliasing writes

#pragma unroll
  for (int ct = 0; ct < 6; ++ct) {
    const int col = c0w + ct * 16 + (lane & 15);
    const float bb = (col < 256) ? boff[col] : battn[col - 256];
#pragma unroll
    for (int rt = 0; rt < 2; ++rt)
#pragma unroll
      for (int r = 0; r < 4; ++r) {
        const int row = rt * 16 + ((lane >> 4) << 2) + r;
        const float vv = acc[rt][ct][r] + bb;
        if (col < 256) offs[row * 256 + col] = vv;
        else           attw[row * 128 + col - 256] = vv;
      }
  }
  __syncthreads();

  // softmax over 16 per (q, m): exactly 256 tasks
  {
    const int q = t >> 3, m = t & 7;
    float v[16], mx = -1e30f;
#pragma unroll
    for (int j = 0; j < 16; ++j) { v[j] = attw[q * 128 + m * 16 + j]; mx = fmaxf(mx, v[j]); }
    float s = 0.f;
#pragma unroll
    for (int j = 0; j < 16; ++j) { v[j] = __expf(v[j] - mx); s += v[j]; }
    const float inv = 1.f / s;
#pragma unroll
    for (int j = 0; j < 16; ++j) attw[q * 128 + m * 16 + j] = v[j] * inv;
  }
  __syncthreads();

  // descriptor build: 32 q x 128 = 4096, coalesced writes
  const size_t dbase = ((size_t)n * QCH + q0c) * 128;
#pragma unroll
  for (int i = 0; i < 16; ++i) {
    const int e = i * 256 + t;
    const int q = e >> 7, j8m = e & 127;
    const int m = j8m & 7, j = j8m >> 3, l = j >> 2;
    const int jo = m * 16 + j;
    const float ox = offs[q * 256 + 2 * jo], oy = offs[q * 256 + 2 * jo + 1];
    const float aw = attw[q * 128 + jo];
    const float rx = refs[q * 8 + l * 2 + 0], ry = refs[q * 8 + l * 2 + 1];
    const int W = 128 >> l;
    const int st_l = ((16384 - (16384 >> (2 * l))) * 4) / 3;  // 0,16384,20480,21504
    const float x = rx * (float)W + ox - 0.5f;
    const float y = ry * (float)W + oy - 0.5f;
    const float x0f = floorf(x), y0f = floorf(y);
    const float fx = x - x0f, fy = y - y0f;
    const int x0 = (int)x0f, y0 = (int)y0f;
    const int x1 = x0 + 1, y1 = y0 + 1;
    const int x0c = min(max(x0, 0), W - 1), x1c = min(max(x1, 0), W - 1);
    const int y0c = min(max(y0, 0), W - 1), y1c = min(max(y1, 0), W - 1);
    float wx0 = 1.f - fx, wx1 = fx, wy0 = 1.f - fy, wy1 = fy;
    if (x0 < 0 || x0 >= W) wx0 = 0.f;
    if (x1 < 0 || x1 >= W) wx1 = 0.f;
    if (y0 < 0 || y0 >= W) wy0 = 0.f;
    if (y1 < 0 || y1 >= W) wy1 = 0.f;
    uint4 dsc;
    dsc.x = (uint32_t)(st_l + y0c * W + x0c) | ((uint32_t)(st_l + y0c * W + x1c) << 16);
    dsc.y = (uint32_t)(st_l + y1c * W + x0c) | ((uint32_t)(st_l + y1c * W + x1c) << 16);
    union { __half2 h; uint32_t u; } p0, p1;
    p0.h = __floats2half2_rn(wx0 * wy0 * aw, wx1 * wy0 * aw);
    p1.h = __floats2half2_rn(wx0 * wy1 * aw, wx1 * wy1 * aw);
    dsc.z = p0.u;
    dsc.w = p1.u;
    descD[dbase + e] = dsc;
  }
}

// ---------------------------------------------------------------------------
// Kernel: pure gather. thread = (q, m, d4); 16 j x 4 corners x 16B fp16
// ---------------------------------------------------------------------------
#define ACC4(RV, WW)                                        \
  {                                                         \
    const float2 f0 = __half22float2(RV.h[0]);              \
    const float2 f1 = __half22float2(RV.h[1]);              \
    const float2 f2 = __half22float2(RV.h[2]);              \
    const float2 f3 = __half22float2(RV.h[3]);              \
    a0 += (WW) * f0.x; a1 += (WW) * f0.y;                   \
    a2 += (WW) * f1.x; a3 += (WW) * f1.y;                   \
    a4 += (WW) * f2.x; a5 += (WW) * f2.y;                   \
    a6 += (WW) * f3.x; a7 += (WW) * f3.y;                   \
  }

__global__ __launch_bounds__(256, 4) void k_gather(
    const uint4* __restrict__ descD, const __half* __restrict__ value,
    short* __restrict__ accB, int qbase) {
  const int t = threadIdx.x;
  const int d4 = t & 3, mB = (t >> 2) & 7, qs = t >> 5;
  const int n  = blockIdx.x / 680;
  const int qc = (blockIdx.x % 680) * 8 + qs;
  const size_t dbase = ((size_t)n * QCH + qc) * 128;
  const char* vb = (const char*)value +
                   (size_t)((uint32_t)((n * 8 + mB) * LEN) * 64u) + d4 * 16;

  float a0 = 0.f, a1 = 0.f, a2 = 0.f, a3 = 0.f;
  float a4 = 0.f, a5 = 0.f, a6 = 0.f, a7 = 0.f;

#pragma unroll 4
  for (int j = 0; j < 16; ++j) {
    const uint4 dsc = descD[dbase + j * 8 + mB];
    const uint32_t i00 = dsc.x & 0xffffu, i01 = dsc.x >> 16;
    const uint32_t i10 = dsc.y & 0xffffu, i11 = dsc.y >> 16;
    union { uint32_t u; __half2 h; } pz, pw;
    pz.u = dsc.z; pw.u = dsc.w;
    const float2 wA = __half22float2(pz.h);
    const float2 wB = __half22float2(pw.h);
    union { uint4 v; __half2 h[4]; } r0, r1, r2, r3;
    r0.v = *(const uint4*)(vb + (size_t)i00 * 64u);
    r1.v = *(const uint4*)(vb + (size_t)i01 * 64u);
    r2.v = *(const uint4*)(vb + (size_t)i10 * 64u);
    r3.v = *(const uint4*)(vb + (size_t)i11 * 64u);
    ACC4(r0, wA.x);
    ACC4(r1, wA.y);
    ACC4(r2, wB.x);
    ACC4(r3, wB.y);
  }
  short8v o;
  o[0] = f2bf(a0); o[1] = f2bf(a1); o[2] = f2bf(a2); o[3] = f2bf(a3);
  o[4] = f2bf(a4); o[5] = f2bf(a5); o[6] = f2bf(a6); o[7] = f2bf(a7);
  *(short8v*)(accB + ((size_t)n * LEN + qbase + qc) * 256 + mB * 32 + d4 * 8) = o;
}

// ---------------------------------------------------------------------------
// Kernel: out = bf16mm(acc, WoT) + bo  (fp32 out)
// ---------------------------------------------------------------------------
__global__ __launch_bounds__(256, 4) void k_outproj(
    const short* __restrict__ accB, const short* __restrict__ WoT,
    const float* __restrict__ bo, float* __restrict__ out) {
  __shared__ __align__(16) char smA[32 * 512];
  const int t = threadIdx.x, lane = t & 63, w = t >> 6;
  const int r0 = blockIdx.x * 32;
  stage_bf16(accB + (size_t)r0 * C, smA, t);
  __syncthreads();

  f32x4 acc[2][4];
#pragma unroll
  for (int a = 0; a < 2; ++a)
#pragma unroll
    for (int b = 0; b < 4; ++b) acc[a][b] = (f32x4){0.f, 0.f, 0.f, 0.f};
  const int c0w = w * 64;
#pragma unroll
  for (int ks = 0; ks < 8; ++ks) {
    const short8v a0 = ldsA(smA, lane, 0, ks);
    const short8v a1 = ldsA(smA, lane, 1, ks);
#pragma unroll
    for (int ct = 0; ct < 4; ++ct) {
      const short8v b = ldB(WoT, c0w + ct * 16 + (lane & 15), ks, lane);
      acc[0][ct] = __builtin_amdgcn_mfma_f32_16x16x32_bf16(a0, b, acc[0][ct], 0, 0, 0);
      acc[1][ct] = __builtin_amdgcn_mfma_f32_16x16x32_bf16(a1, b, acc[1][ct], 0, 0, 0);
    }
  }
#pragma unroll
  for (int ct = 0; ct < 4; ++ct) {
    const int col = c0w + ct * 16 + (lane & 15);
    const float bb = bo[col];
#pragma unroll
    for (int rt = 0; rt < 2; ++rt)
#pragma unroll
      for (int r = 0; r < 4; ++r) {
        const int row = r0 + rt * 16 + ((lane >> 4) << 2) + r;
        out[(size_t)row * C + col] = acc[rt][ct][r] + bb;
      }
  }
}

// ---------------------------------------------------------------------------
extern "C" void kernel_launch(void* const* d_in, const int* in_sizes, int n_in,
                              void* d_out, int out_size, void* d_ws, size_t ws_size,
                              hipStream_t stream) {
  const float* query = (const float*)d_in[0];
  const float* refp  = (const float*)d_in[1];
  const float* infl  = (const float*)d_in[2];
  const float* Woff  = (const float*)d_in[3];
  const float* boff  = (const float*)d_in[4];
  const float* Wattn = (const float*)d_in[5];
  const float* battn = (const float*)d_in[6];
  const float* Wval  = (const float*)d_in[7];
  const float* bval  = (const float*)d_in[8];
  const float* Wout  = (const float*)d_in[9];
  const float* bout  = (const float*)d_in[10];
  float* out = (float*)d_out;

  char* ws = (char*)d_ws;
  __half* value = (__half*)ws;                   // 22,282,240 B
  short*  accB  = (short*)(ws + 22282240);       // 22,282,240 B
  uint4*  descD = (uint4*)(ws + 44564480);       // 22,282,240 B
  short*  WvT   = (short*)(ws + 66846720);       // 131,072 B
  short*  WdT   = (short*)(ws + 66977792);       // 196,608 B
  short*  WoT   = (short*)(ws + 67174400);       // 131,072 B  (total 67.3 MB)

  k_tcast<<<dim3(8, 8), 256, 0, stream>>>(Wval, WvT, 256);
  k_tcast<<<dim3(8, 8), 256, 0, stream>>>(Woff, WdT, 256);
  k_tcast<<<dim3(4, 8), 256, 0, stream>>>(Wattn, WdT + (size_t)256 * 256, 128);
  k_tcast<<<dim3(8, 8), 256, 0, stream>>>(Wout, WoT, 256);

  k_valproj<<<(NB * LEN) / 32, 256, 0, stream>>>(infl, WvT, bval, value);

  for (int c = 0; c < 4; ++c) {
    k_desc<<<2 * (QCH / 32), 256, 0, stream>>>(query, refp, WdT, boff, battn,
                                               descD, c * QCH);
    k_gather<<<2 * (QCH / 8), 256, 0, stream>>>(descD, value, accB, c * QCH);
  }

  k_outproj<<<(NB * LEN) / 32, 256, 0, stream>>>(accB, WoT, bout, out);
}

// Round 5
// 298.420 us; speedup vs baseline: 2.1847x; 1.0168x over previous
//
#include <hip/hip_runtime.h>
#include <hip/hip_fp16.h>
#include <math.h>
#include <stdint.h>

// MSDeformAttn. N=2, C=256, M=8, L=4, P=4, D=32, LEN=21760
// R5: coalesced epilogues for valproj/outproj via padded-LDS transpose;
//     merged prepack kernel. GEMMs bf16 MFMA; value fp16; acc bf16.

constexpr int NB  = 2;
constexpr int C   = 256;
constexpr int M   = 8;
constexpr int D   = 32;
constexpr int LEN = 21760;
constexpr int QCH = LEN / 4;   // 5440 queries per chunk (per batch)

typedef __attribute__((ext_vector_type(8))) short short8v;
typedef __attribute__((ext_vector_type(4))) float f32x4;

__device__ __forceinline__ short f2bf(float x) {
  uint32_t u = __float_as_uint(x);
  u = (u + 0x7fffu + ((u >> 16) & 1u)) >> 16;
  return (short)u;
}

// ---------------------------------------------------------------------------
// Prepack (all 4 weight mats in one launch): dst[c][k] = (bf16) src[k][c]
// ---------------------------------------------------------------------------
__global__ __launch_bounds__(256) void k_tcast4(
    const float* __restrict__ s0, const float* __restrict__ s1,
    const float* __restrict__ s2, const float* __restrict__ s3,
    short* __restrict__ d0, short* __restrict__ d1,
    short* __restrict__ d2, short* __restrict__ d3) {
  __shared__ float tile[32][33];
  const int z = blockIdx.z;
  const float* src = (z == 0) ? s0 : (z == 1) ? s1 : (z == 2) ? s2 : s3;
  short* dst = (z == 0) ? d0 : (z == 1) ? d1 : (z == 2) ? d2 : d3;
  const int ncols = (z == 2) ? 128 : 256;
  const int c0 = blockIdx.x * 32, k0 = blockIdx.y * 32;
  if (c0 >= ncols) return;
  const int t = threadIdx.x, tx = t & 31, ty = t >> 5;
#pragma unroll
  for (int i = 0; i < 4; ++i)
    tile[ty + i * 8][tx] = src[(size_t)(k0 + ty + i * 8) * ncols + c0 + tx];
  __syncthreads();
#pragma unroll
  for (int i = 0; i < 4; ++i)
    dst[(size_t)(c0 + ty + i * 8) * 256 + k0 + tx] = f2bf(tile[tx][ty + i * 8]);
}

// ---------------------------------------------------------------------------
// LDS staging (32 rows x 256 k, bf16, XOR-swizzled) + fragment loads
// ---------------------------------------------------------------------------
__device__ __forceinline__ void stage_cast(const float* __restrict__ p, char* sm, int t) {
  const int r = t >> 3, seg = t & 7;
  const float4* s = (const float4*)(p + (size_t)r * C + seg * 32);
  short v[32];
#pragma unroll
  for (int i = 0; i < 8; ++i) {
    float4 f = s[i];
    v[i * 4 + 0] = f2bf(f.x); v[i * 4 + 1] = f2bf(f.y);
    v[i * 4 + 2] = f2bf(f.z); v[i * 4 + 3] = f2bf(f.w);
  }
#pragma unroll
  for (int i = 0; i < 4; ++i) {
    const int kb = (seg * 32 + i * 8) * 2;
    *(int4*)(sm + r * 512 + (kb ^ ((r & 7) << 4))) = ((const int4*)v)[i];
  }
}

__device__ __forceinline__ void stage_bf16(const short* __restrict__ p, char* sm, int t) {
  const int r = t >> 3, seg = t & 7;
  const int4* s = (const int4*)(p + (size_t)r * C + seg * 32);
#pragma unroll
  for (int i = 0; i < 4; ++i) {
    const int kb = (seg * 32 + i * 8) * 2;
    *(int4*)(sm + r * 512 + (kb ^ ((r & 7) << 4))) = s[i];
  }
}

__device__ __forceinline__ short8v ldsA(const char* sm, int lane, int rt, int ks) {
  const int row = rt * 16 + (lane & 15);
  const int kb  = ks * 64 + ((lane >> 4) << 4);
  const int4 v = *(const int4*)(sm + row * 512 + (kb ^ ((row & 7) << 4)));
  union { int4 i; short8v s; } u; u.i = v; return u.s;
}

__device__ __forceinline__ short8v ldB(const short* __restrict__ WT, int col, int ks, int lane) {
  const int kidx = ks * 32 + ((lane >> 4) << 3);
  const int4 v = *(const int4*)(WT + (size_t)col * 256 + kidx);
  union { int4 i; short8v s; } u; u.i = v; return u.s;
}

// ---------------------------------------------------------------------------
// Kernel: value = bf16mm(input_flatten, WvT) + bv -> fp16 value[n][m][pix][d]
// Coalesced epilogue via padded LDS transpose (stride 260 words).
// ---------------------------------------------------------------------------
__global__ __launch_bounds__(256, 4) void k_valproj(
    const float* __restrict__ infl, const short* __restrict__ WvT,
    const float* __restrict__ bv, __half* __restrict__ value) {
  __shared__ __align__(16) char smem[33280];
  char*  smA = smem;
  float* smf = (float*)smem;   // [32][260] f32, aliases smA after k-loop

  const int t = threadIdx.x, lane = t & 63, w = t >> 6;
  const int r0 = blockIdx.x * 32;
  stage_cast(infl + (size_t)r0 * C, smA, t);
  __syncthreads();

  f32x4 acc[2][4];
#pragma unroll
  for (int a = 0; a < 2; ++a)
#pragma unroll
    for (int b = 0; b < 4; ++b) acc[a][b] = (f32x4){0.f, 0.f, 0.f, 0.f};
  const int c0w = w * 64;
#pragma unroll
  for (int ks = 0; ks < 8; ++ks) {
    const short8v a0 = ldsA(smA, lane, 0, ks);
    const short8v a1 = ldsA(smA, lane, 1, ks);
#pragma unroll
    for (int ct = 0; ct < 4; ++ct) {
      const short8v b = ldB(WvT, c0w + ct * 16 + (lane & 15), ks, lane);
      acc[0][ct] = __builtin_amdgcn_mfma_f32_16x16x32_bf16(a0, b, acc[0][ct], 0, 0, 0);
      acc[1][ct] = __builtin_amdgcn_mfma_f32_16x16x32_bf16(a1, b, acc[1][ct], 0, 0, 0);
    }
  }
  __syncthreads();   // A-tile reads done; alias as smf

#pragma unroll
  for (int ct = 0; ct < 4; ++ct) {
    const int col = c0w + ct * 16 + (lane & 15);
    const float bb = bv[col];
#pragma unroll
    for (int rt = 0; rt < 2; ++rt)
#pragma unroll
      for (int r = 0; r < 4; ++r) {
        const int pix = rt * 16 + ((lane >> 4) << 2) + r;
        smf[pix * 260 + col] = acc[rt][ct][r] + bb;
      }
  }
  __syncthreads();

  const int n = (blockIdx.x >= (LEN / 32)) ? 1 : 0;
  const int pix0 = r0 - n * LEN;
#pragma unroll
  for (int i = 0; i < 4; ++i) {
    const int f = i * 256 + t;
    const int m = f >> 7, rem = f & 127;
    const int pix = rem >> 2, d8 = rem & 3;
    const float* p = &smf[pix * 260 + m * 32 + d8 * 8];
    const float4 lo = *(const float4*)p;
    const float4 hi = *(const float4*)(p + 4);
    union { uint4 u; __half h[8]; } o;
    o.h[0] = __float2half(lo.x); o.h[1] = __float2half(lo.y);
    o.h[2] = __float2half(lo.z); o.h[3] = __float2half(lo.w);
    o.h[4] = __float2half(hi.x); o.h[5] = __float2half(hi.y);
    o.h[6] = __float2half(hi.z); o.h[7] = __float2half(hi.w);
    *(uint4*)((char*)value +
              ((size_t)((n * 8 + m) * LEN + pix0 + pix)) * 64 + d8 * 16) = o.u;
  }
}

// ---------------------------------------------------------------------------
// Kernel: offsets/attn GEMM (bf16 MFMA) + softmax + descriptor build
// ---------------------------------------------------------------------------
__global__ __launch_bounds__(256, 3) void k_desc(
    const float* __restrict__ query, const float* __restrict__ refp,
    const short* __restrict__ WdT, const float* __restrict__ boff,
    const float* __restrict__ battn, uint4* __restrict__ descD, int qbase) {
  __shared__ __align__(16) char smem[50176];
  char*  smA  = smem;                       // [32][512] bf16 A-tile
  float* offs = (float*)smem;               // [32][256] (aliases smA; used later)
  float* attw = (float*)(smem + 32768);     // [32][128]
  float* refs = (float*)(smem + 49152);     // [32][8]

  const int t = threadIdx.x, lane = t & 63, w = t >> 6;
  const int n   = blockIdx.x / 170;
  const int q0c = (blockIdx.x % 170) * 32;
  const size_t qrow = (size_t)n * LEN + qbase + q0c;

  refs[t] = refp[qrow * 8 + t];
  stage_cast(query + qrow * C, smA, t);
  __syncthreads();

  f32x4 acc[2][6];
#pragma unroll
  for (int a = 0; a < 2; ++a)
#pragma unroll
    for (int b = 0; b < 6; ++b) acc[a][b] = (f32x4){0.f, 0.f, 0.f, 0.f};
  const int c0w = w * 96;
#pragma unroll
  for (int ks = 0; ks < 8; ++ks) {
    const short8v a0 = ldsA(smA, lane, 0, ks);
    const short8v a1 = ldsA(smA, lane, 1, ks);
#pragma unroll
    for (int ct = 0; ct < 6; ++ct) {
      const short8v b = ldB(WdT, c0w + ct * 16 + (lane & 15), ks, lane);
      acc[0][ct] = __builtin_amdgcn_mfma_f32_16x16x32_bf16(a0, b, acc[0][ct], 0, 0, 0);
      acc[1][ct] = __builtin_amdgcn_mfma_f32_16x16x32_bf16(a1, b, acc[1][ct], 0, 0, 0);
    }
  }
  __syncthreads();   // all LDS A reads complete before aliasing writes

#pragma unroll
  for (int ct = 0; ct < 6; ++ct) {
    const int col = c0w + ct * 16 + (lane & 15);
    const float bb = (col < 256) ? boff[col] : battn[col - 256];
#pragma unroll
    for (int rt = 0; rt < 2; ++rt)
#pragma unroll
      for (int r = 0; r < 4; ++r) {
        const int row = rt * 16 + ((lane >> 4) << 2) + r;
        const float vv = acc[rt][ct][r] + bb;
        if (col < 256) offs[row * 256 + col] = vv;
        else           attw[row * 128 + col - 256] = vv;
      }
  }
  __syncthreads();

  // softmax over 16 per (q, m): exactly 256 tasks
  {
    const int q = t >> 3, m = t & 7;
    float v[16], mx = -1e30f;
#pragma unroll
    for (int j = 0; j < 16; ++j) { v[j] = attw[q * 128 + m * 16 + j]; mx = fmaxf(mx, v[j]); }
    float s = 0.f;
#pragma unroll
    for (int j = 0; j < 16; ++j) { v[j] = __expf(v[j] - mx); s += v[j]; }
    const float inv = 1.f / s;
#pragma unroll
    for (int j = 0; j < 16; ++j) attw[q * 128 + m * 16 + j] = v[j] * inv;
  }
  __syncthreads();

  // descriptor build: 32 q x 128 = 4096, coalesced writes
  const size_t dbase = ((size_t)n * QCH + q0c) * 128;
#pragma unroll
  for (int i = 0; i < 16; ++i) {
    const int e = i * 256 + t;
    const int q = e >> 7, j8m = e & 127;
    const int m = j8m & 7, j = j8m >> 3, l = j >> 2;
    const int jo = m * 16 + j;
    const float ox = offs[q * 256 + 2 * jo], oy = offs[q * 256 + 2 * jo + 1];
    const float aw = attw[q * 128 + jo];
    const float rx = refs[q * 8 + l * 2 + 0], ry = refs[q * 8 + l * 2 + 1];
    const int W = 128 >> l;
    const int st_l = ((16384 - (16384 >> (2 * l))) * 4) / 3;  // 0,16384,20480,21504
    const float x = rx * (float)W + ox - 0.5f;
    const float y = ry * (float)W + oy - 0.5f;
    const float x0f = floorf(x), y0f = floorf(y);
    const float fx = x - x0f, fy = y - y0f;
    const int x0 = (int)x0f, y0 = (int)y0f;
    const int x1 = x0 + 1, y1 = y0 + 1;
    const int x0c = min(max(x0, 0), W - 1), x1c = min(max(x1, 0), W - 1);
    const int y0c = min(max(y0, 0), W - 1), y1c = min(max(y1, 0), W - 1);
    float wx0 = 1.f - fx, wx1 = fx, wy0 = 1.f - fy, wy1 = fy;
    if (x0 < 0 || x0 >= W) wx0 = 0.f;
    if (x1 < 0 || x1 >= W) wx1 = 0.f;
    if (y0 < 0 || y0 >= W) wy0 = 0.f;
    if (y1 < 0 || y1 >= W) wy1 = 0.f;
    uint4 dsc;
    dsc.x = (uint32_t)(st_l + y0c * W + x0c) | ((uint32_t)(st_l + y0c * W + x1c) << 16);
    dsc.y = (uint32_t)(st_l + y1c * W + x0c) | ((uint32_t)(st_l + y1c * W + x1c) << 16);
    union { __half2 h; uint32_t u; } p0, p1;
    p0.h = __floats2half2_rn(wx0 * wy0 * aw, wx1 * wy0 * aw);
    p1.h = __floats2half2_rn(wx0 * wy1 * aw, wx1 * wy1 * aw);
    dsc.z = p0.u;
    dsc.w = p1.u;
    descD[dbase + e] = dsc;
  }
}

// ---------------------------------------------------------------------------
// Kernel: pure gather. thread = (q, m, d4); 16 j x 4 corners x 16B fp16
// ---------------------------------------------------------------------------
#define ACC4(RV, WW)                                        \
  {                                                         \
    const float2 f0 = __half22float2(RV.h[0]);              \
    const float2 f1 = __half22float2(RV.h[1]);              \
    const float2 f2 = __half22float2(RV.h[2]);              \
    const float2 f3 = __half22float2(RV.h[3]);              \
    a0 += (WW) * f0.x; a1 += (WW) * f0.y;                   \
    a2 += (WW) * f1.x; a3 += (WW) * f1.y;                   \
    a4 += (WW) * f2.x; a5 += (WW) * f2.y;                   \
    a6 += (WW) * f3.x; a7 += (WW) * f3.y;                   \
  }

__global__ __launch_bounds__(256, 4) void k_gather(
    const uint4* __restrict__ descD, const __half* __restrict__ value,
    short* __restrict__ accB, int qbase) {
  const int t = threadIdx.x;
  const int d4 = t & 3, mB = (t >> 2) & 7, qs = t >> 5;
  const int n  = blockIdx.x / 680;
  const int qc = (blockIdx.x % 680) * 8 + qs;
  const size_t dbase = ((size_t)n * QCH + qc) * 128;
  const char* vb = (const char*)value +
                   (size_t)((uint32_t)((n * 8 + mB) * LEN) * 64u) + d4 * 16;

  float a0 = 0.f, a1 = 0.f, a2 = 0.f, a3 = 0.f;
  float a4 = 0.f, a5 = 0.f, a6 = 0.f, a7 = 0.f;

#pragma unroll 4
  for (int j = 0; j < 16; ++j) {
    const uint4 dsc = descD[dbase + j * 8 + mB];
    const uint32_t i00 = dsc.x & 0xffffu, i01 = dsc.x >> 16;
    const uint32_t i10 = dsc.y & 0xffffu, i11 = dsc.y >> 16;
    union { uint32_t u; __half2 h; } pz, pw;
    pz.u = dsc.z; pw.u = dsc.w;
    const float2 wA = __half22float2(pz.h);
    const float2 wB = __half22float2(pw.h);
    union { uint4 v; __half2 h[4]; } r0, r1, r2, r3;
    r0.v = *(const uint4*)(vb + (size_t)i00 * 64u);
    r1.v = *(const uint4*)(vb + (size_t)i01 * 64u);
    r2.v = *(const uint4*)(vb + (size_t)i10 * 64u);
    r3.v = *(const uint4*)(vb + (size_t)i11 * 64u);
    ACC4(r0, wA.x);
    ACC4(r1, wA.y);
    ACC4(r2, wB.x);
    ACC4(r3, wB.y);
  }
  short8v o;
  o[0] = f2bf(a0); o[1] = f2bf(a1); o[2] = f2bf(a2); o[3] = f2bf(a3);
  o[4] = f2bf(a4); o[5] = f2bf(a5); o[6] = f2bf(a6); o[7] = f2bf(a7);
  *(short8v*)(accB + ((size_t)n * LEN + qbase + qc) * 256 + mB * 32 + d4 * 8) = o;
}

// ---------------------------------------------------------------------------
// Kernel: out = bf16mm(acc, WoT) + bo  (fp32 out), coalesced epilogue
// ---------------------------------------------------------------------------
__global__ __launch_bounds__(256, 4) void k_outproj(
    const short* __restrict__ accB, const short* __restrict__ WoT,
    const float* __restrict__ bo, float* __restrict__ out) {
  __shared__ __align__(16) char smem[33280];
  char*  smA = smem;
  float* smf = (float*)smem;   // [32][260] f32, aliases smA after k-loop

  const int t = threadIdx.x, lane = t & 63, w = t >> 6;
  const int r0 = blockIdx.x * 32;
  stage_bf16(accB + (size_t)r0 * C, smA, t);
  __syncthreads();

  f32x4 acc[2][4];
#pragma unroll
  for (int a = 0; a < 2; ++a)
#pragma unroll
    for (int b = 0; b < 4; ++b) acc[a][b] = (f32x4){0.f, 0.f, 0.f, 0.f};
  const int c0w = w * 64;
#pragma unroll
  for (int ks = 0; ks < 8; ++ks) {
    const short8v a0 = ldsA(smA, lane, 0, ks);
    const short8v a1 = ldsA(smA, lane, 1, ks);
#pragma unroll
    for (int ct = 0; ct < 4; ++ct) {
      const short8v b = ldB(WoT, c0w + ct * 16 + (lane & 15), ks, lane);
      acc[0][ct] = __builtin_amdgcn_mfma_f32_16x16x32_bf16(a0, b, acc[0][ct], 0, 0, 0);
      acc[1][ct] = __builtin_amdgcn_mfma_f32_16x16x32_bf16(a1, b, acc[1][ct], 0, 0, 0);
    }
  }
  __syncthreads();

#pragma unroll
  for (int ct = 0; ct < 4; ++ct) {
    const int col = c0w + ct * 16 + (lane & 15);
    const float bb = bo[col];
#pragma unroll
    for (int rt = 0; rt < 2; ++rt)
#pragma unroll
      for (int r = 0; r < 4; ++r) {
        const int row = rt * 16 + ((lane >> 4) << 2) + r;
        smf[row * 260 + col] = acc[rt][ct][r] + bb;
      }
  }
  __syncthreads();

#pragma unroll
  for (int i = 0; i < 8; ++i) {
    const int f = i * 256 + t;
    const int row = f >> 6, cu = f & 63;
    const float4 v = *(const float4*)&smf[row * 260 + cu * 4];
    *(float4*)&out[(size_t)(r0 + row) * C + cu * 4] = v;
  }
}

// ---------------------------------------------------------------------------
extern "C" void kernel_launch(void* const* d_in, const int* in_sizes, int n_in,
                              void* d_out, int out_size, void* d_ws, size_t ws_size,
                              hipStream_t stream) {
  const float* query = (const float*)d_in[0];
  const float* refp  = (const float*)d_in[1];
  const float* infl  = (const float*)d_in[2];
  const float* Woff  = (const float*)d_in[3];
  const float* boff  = (const float*)d_in[4];
  const float* Wattn = (const float*)d_in[5];
  const float* battn = (const float*)d_in[6];
  const float* Wval  = (const float*)d_in[7];
  const float* bval  = (const float*)d_in[8];
  const float* Wout  = (const float*)d_in[9];
  const float* bout  = (const float*)d_in[10];
  float* out = (float*)d_out;

  char* ws = (char*)d_ws;
  __half* value = (__half*)ws;                   // 22,282,240 B
  short*  accB  = (short*)(ws + 22282240);       // 22,282,240 B
  uint4*  descD = (uint4*)(ws + 44564480);       // 22,282,240 B
  short*  WvT   = (short*)(ws + 66846720);       // 131,072 B
  short*  WdT   = (short*)(ws + 66977792);       // 196,608 B
  short*  WoT   = (short*)(ws + 67174400);       // 131,072 B  (total 67.3 MB)

  k_tcast4<<<dim3(8, 8, 4), 256, 0, stream>>>(
      Wval, Woff, Wattn, Wout, WvT, WdT, WdT + (size_t)256 * 256, WoT);

  k_valproj<<<(NB * LEN) / 32, 256, 0, stream>>>(infl, WvT, bval, value);

  for (int c = 0; c < 4; ++c) {
    k_desc<<<2 * (QCH / 32), 256, 0, stream>>>(query, refp, WdT, boff, battn,
                                               descD, c * QCH);
    k_gather<<<2 * (QCH / 8), 256, 0, stream>>>(descD, value, accB, c * QCH);
  }

  k_outproj<<<(NB * LEN) / 32, 256, 0, stream>>>(accB, WoT, bout, out);
}